// Round 1
// baseline (508.128 us; speedup 1.0000x reference)
//
#include <hip/hip_runtime.h>
#include <stdint.h>

#define B_   8
#define N_   256
#define D_   128
#define MID_ 128
#define FEAT_ 256

typedef __attribute__((ext_vector_type(4))) float  floatx4;
typedef __attribute__((ext_vector_type(8))) __bf16 bf16x8;
typedef __attribute__((ext_vector_type(8))) short  shortx8;

__device__ __forceinline__ unsigned short f2bf(float f) {
    union { float f; unsigned int u; } v; v.f = f;
    unsigned int u = v.u;
    u += 0x7FFFu + ((u >> 16) & 1u);           // round-to-nearest-even
    return (unsigned short)(u >> 16);
}

__device__ __forceinline__ floatx4 mfma16(bf16x8 a, bf16x8 b, floatx4 c) {
    return __builtin_amdgcn_mfma_f32_16x16x32_bf16(a, b, c, 0, 0, 0);
}

// ---------------- kernel G: gplus[b][m] = g@Wg + bg + b1 + be ----------------
__global__ void kG(const float* __restrict__ g, const float* __restrict__ Wg,
                   const float* __restrict__ bg, const float* __restrict__ b1,
                   const float* __restrict__ be, float* __restrict__ gplus) {
    int t = threadIdx.x;               // 1024 threads
    int b = t >> 7, m = t & 127;
    float acc = 0.f;
    for (int k = 0; k < D_; ++k)
        acc += g[b * D_ + k] * Wg[k * MID_ + m];
    gplus[b * MID_ + m] = acc + bg[m] + b1[m] + be[m];
}

// ---------------- kernel A: per-node GEMMs (fp32) ----------------
// C    = feat@W1 + gplus         (msg1 + msg_g + b1 + be)
// msg2 = feat@W2 + b2
// retA = feat@Wo1 + bo1 + bo2
__global__ void kA(const float* __restrict__ nfeat, const float* __restrict__ hidden,
                   const float* __restrict__ W1, const float* __restrict__ W2,
                   const float* __restrict__ Wo1,
                   const float* __restrict__ b2, const float* __restrict__ bo1,
                   const float* __restrict__ bo2, const float* __restrict__ gplus,
                   float* __restrict__ C, float* __restrict__ msg2,
                   float* __restrict__ retA) {
    __shared__ float feat_sh[4][FEAT_];
    int t  = threadIdx.x;              // 256 threads, 4 rows/block
    int R0 = blockIdx.x * 4;
    {
        int r = t >> 6;                // 0..3
        int c = (t & 63) * 4;          // 0..252
        int R = R0 + r;
        int b = R >> 8, n = R & 255;
        const float* src = (c < D_) ? &nfeat[(b * N_ + n) * D_ + c]
                                    : &hidden[(b * N_ + n) * D_ + (c - D_)];
        *(float4*)&feat_sh[r][c] = *(const float4*)src;
    }
    __syncthreads();
    int m = t & 127, h = t >> 7;
    float a10 = 0, a11 = 0, a20 = 0, a21 = 0, ao0 = 0, ao1 = 0;
    for (int k = 0; k < FEAT_; ++k) {
        float w1 = W1[k * MID_ + m];
        float w2 = W2[k * MID_ + m];
        float wo = Wo1[k * MID_ + m];
        float f0 = feat_sh[h * 2][k];
        float f1 = feat_sh[h * 2 + 1][k];
        a10 += f0 * w1; a11 += f1 * w1;
        a20 += f0 * w2; a21 += f1 * w2;
        ao0 += f0 * wo; ao1 += f1 * wo;
    }
#pragma unroll
    for (int r = 0; r < 2; ++r) {
        int R = R0 + h * 2 + r;
        int b = R >> 8;
        float v1 = (r == 0) ? a10 : a11;
        float v2 = (r == 0) ? a20 : a21;
        float vo = (r == 0) ? ao0 : ao1;
        C[R * MID_ + m]    = v1 + gplus[b * MID_ + m];
        msg2[R * MID_ + m] = v2 + b2[m];
        retA[R * MID_ + m] = vo + bo1[m] + bo2[m];
    }
}

// ---------------- kernel B: fused msg_e GEMM + broadcast-add + mask-max + out ----------------
// one block per (b, j); 256 threads = 4 waves; wave w owns i in [pass*128 + w*32, +32)
__global__ void __launch_bounds__(256, 2)
kB(const float* __restrict__ e, const float* __restrict__ We,
   const float* __restrict__ adj, const float* __restrict__ C,
   const float* __restrict__ msg2, const float* __restrict__ retA,
   const float* __restrict__ Wo2, float* __restrict__ out) {
    __shared__ unsigned short Wb[4 * 8 * 64 * 8];   // [kstep][ntile][lane][jj] bf16, 32 KB
    __shared__ float adj_sh[N_];
    __shared__ float C_sh[MID_];
    __shared__ float wmax[4][MID_];
    __shared__ float msgs_sh[MID_];
    __shared__ float part[2][MID_];

    int t = threadIdx.x;
    int b = blockIdx.x >> 8, j = blockIdx.x & 255;

    // ---- stage We into fragment-swizzled bf16 LDS ----
    for (int idx = t; idx < 16384; idx += 256) {
        int mm = idx & 127;            // coalesced global read: mm fastest
        int k  = idx >> 7;
        int kstep = k >> 5, quad = (k >> 3) & 3, jj = k & 7;
        int nt = mm >> 4, n16 = mm & 15;
        int lane_w = quad * 16 + n16;
        Wb[(((kstep * 8 + nt) * 64 + lane_w) * 8) + jj] = f2bf(We[k * MID_ + mm]);
    }
    adj_sh[t] = adj[b * N_ * N_ + t * N_ + j];
    if (t < 128) C_sh[t] = C[(b * N_ + j) * MID_ + t];
    __syncthreads();

    int lane = t & 63, w = t >> 6;
    int n16 = lane & 15, quad = lane >> 4;
    const float* erow = e + (size_t)(b * N_) * (N_ * D_) + (size_t)j * D_;
    const float* m2p  = msg2 + (size_t)(b * N_) * MID_;

    float rm[8];
#pragma unroll
    for (int nt = 0; nt < 8; ++nt) rm[nt] = -INFINITY;

    for (int pass = 0; pass < 2; ++pass) {
        int ibase = pass * 128 + w * 32;
        floatx4 acc[2][8];
#pragma unroll
        for (int it = 0; it < 2; ++it)
#pragma unroll
            for (int nt = 0; nt < 8; ++nt) acc[it][nt] = (floatx4)0.f;

#pragma unroll
        for (int ks = 0; ks < 4; ++ks) {
            bf16x8 af[2];
#pragma unroll
            for (int it = 0; it < 2; ++it) {
                int i = ibase + it * 16 + n16;
                const float* p = erow + (size_t)i * (N_ * D_) + ks * 32 + quad * 8;
                float4 v0 = *(const float4*)p;
                float4 v1 = *(const float4*)(p + 4);
                shortx8 s;
                s[0] = (short)f2bf(v0.x); s[1] = (short)f2bf(v0.y);
                s[2] = (short)f2bf(v0.z); s[3] = (short)f2bf(v0.w);
                s[4] = (short)f2bf(v1.x); s[5] = (short)f2bf(v1.y);
                s[6] = (short)f2bf(v1.z); s[7] = (short)f2bf(v1.w);
                af[it] = __builtin_bit_cast(bf16x8, s);
            }
#pragma unroll
            for (int nt = 0; nt < 8; ++nt) {
                const shortx8* bp = (const shortx8*)&Wb[((ks * 8 + nt) * 64 + lane) * 8];
                bf16x8 bf = __builtin_bit_cast(bf16x8, *bp);
                acc[0][nt] = mfma16(af[0], bf, acc[0][nt]);
                acc[1][nt] = mfma16(af[1], bf, acc[1][nt]);
            }
        }
        // epilogue for this pass: add msg2 + C, mask, running max over i
#pragma unroll
        for (int it = 0; it < 2; ++it) {
            int i0 = ibase + it * 16 + quad * 4;
#pragma unroll
            for (int nt = 0; nt < 8; ++nt) {
                int mm = nt * 16 + n16;
                float Cm = C_sh[mm];
#pragma unroll
                for (int r = 0; r < 4; ++r) {
                    int i = i0 + r;
                    float val = (acc[it][nt][r] + Cm + m2p[i * MID_ + mm]) * adj_sh[i];
                    rm[nt] = fmaxf(rm[nt], val);
                }
            }
        }
    }
    // reduce across quads (i dimension), then across waves via LDS
#pragma unroll
    for (int nt = 0; nt < 8; ++nt) {
        float v = rm[nt];
        v = fmaxf(v, __shfl_xor(v, 16, 64));
        v = fmaxf(v, __shfl_xor(v, 32, 64));
        rm[nt] = v;
    }
    if (quad == 0) {
#pragma unroll
        for (int nt = 0; nt < 8; ++nt) wmax[w][nt * 16 + n16] = rm[nt];
    }
    __syncthreads();
    int m = t & 127, h = t >> 7;
    if (t < 128) {
        float mx = fmaxf(fmaxf(wmax[0][m], wmax[1][m]), fmaxf(wmax[2][m], wmax[3][m]));
        msgs_sh[m] = mx;
    }
    __syncthreads();
    // fused: ret = retA + msgs @ Wo2   (split-k over the two thread halves)
    float a2 = 0.f;
    for (int k = h * 64; k < h * 64 + 64; ++k)
        a2 += msgs_sh[k] * Wo2[k * MID_ + m];
    part[h][m] = a2;
    __syncthreads();
    if (t < 128) {
        int R = b * N_ + j;
        out[(size_t)R * MID_ + m] = retA[R * MID_ + m] + part[0][m] + part[1][m];
    }
}

extern "C" void kernel_launch(void* const* d_in, const int* in_sizes, int n_in,
                              void* d_out, int out_size, void* d_ws, size_t ws_size,
                              hipStream_t stream) {
    (void)in_sizes; (void)n_in; (void)out_size; (void)ws_size;
    const float* hidden = (const float*)d_in[0];
    const float* nfeat  = (const float*)d_in[1];
    const float* e      = (const float*)d_in[2];
    const float* g      = (const float*)d_in[3];
    const float* adj    = (const float*)d_in[4];
    const float* W1  = (const float*)d_in[5];
    const float* b1  = (const float*)d_in[6];
    const float* W2  = (const float*)d_in[7];
    const float* b2  = (const float*)d_in[8];
    const float* We  = (const float*)d_in[9];
    const float* be  = (const float*)d_in[10];
    const float* Wg  = (const float*)d_in[11];
    const float* bg  = (const float*)d_in[12];
    const float* Wo1 = (const float*)d_in[13];
    const float* bo1 = (const float*)d_in[14];
    const float* Wo2 = (const float*)d_in[15];
    const float* bo2 = (const float*)d_in[16];
    float* outp = (float*)d_out;

    float* ws    = (float*)d_ws;
    float* gplus = ws;                       // 1024
    float* C     = ws + 1024;                // 262144
    float* msg2  = C + 262144;               // 262144
    float* retA  = msg2 + 262144;            // 262144  (total ~3 MB)

    kG<<<1, 1024, 0, stream>>>(g, Wg, bg, b1, be, gplus);
    kA<<<512, 256, 0, stream>>>(nfeat, hidden, W1, W2, Wo1, b2, bo1, bo2, gplus,
                                C, msg2, retA);
    kB<<<2048, 256, 0, stream>>>(e, We, adj, C, msg2, retA, Wo2, outp);
}

// Round 2
// 446.411 us; speedup vs baseline: 1.1383x; 1.1383x over previous
//
#include <hip/hip_runtime.h>
#include <stdint.h>

#define B_   8
#define N_   256
#define D_   128
#define MID_ 128
#define FEAT_ 256

typedef __attribute__((ext_vector_type(4))) float  floatx4;
typedef __attribute__((ext_vector_type(8))) __bf16 bf16x8;

__device__ __forceinline__ floatx4 mfma16(bf16x8 a, bf16x8 b, floatx4 c) {
    return __builtin_amdgcn_mfma_f32_16x16x32_bf16(a, b, c, 0, 0, 0);
}

// HW bf16 convert (compiler emits v_cvt_pk_bf16_f32 on gfx950), RNE.
__device__ __forceinline__ bf16x8 cvt8(floatx4 a, floatx4 b) {
    bf16x8 r;
    r[0] = (__bf16)a[0]; r[1] = (__bf16)a[1]; r[2] = (__bf16)a[2]; r[3] = (__bf16)a[3];
    r[4] = (__bf16)b[0]; r[5] = (__bf16)b[1]; r[6] = (__bf16)b[2]; r[7] = (__bf16)b[3];
    return r;
}

// ---------------- kernel G: gplus[b][m] = g@Wg + bg + b1 + be ----------------
__global__ void kG(const float* __restrict__ g, const float* __restrict__ Wg,
                   const float* __restrict__ bg, const float* __restrict__ b1,
                   const float* __restrict__ be, float* __restrict__ gplus) {
    int t = threadIdx.x;               // 1024 threads
    int b = t >> 7, m = t & 127;
    float acc = 0.f;
    for (int k = 0; k < D_; ++k)
        acc += g[b * D_ + k] * Wg[k * MID_ + m];
    gplus[b * MID_ + m] = acc + bg[m] + b1[m] + be[m];
}

// ---------------- kernel A: per-node GEMMs via MFMA (bf16) ----------------
// grid (32 row-tiles of 64, 3 weights). A = W^T (swizzled LDS), B = feat rows.
// wid 0: C = feat@W1 + gplus ; wid 1: msg2 = feat@W2 + b2 ; wid 2: retA = feat@Wo1+bo1+bo2
__global__ void __launch_bounds__(256)
kA(const float* __restrict__ nfeat, const float* __restrict__ hidden,
   const float* __restrict__ W1, const float* __restrict__ W2,
   const float* __restrict__ Wo1, const float* __restrict__ gplus,
   const float* __restrict__ b2, const float* __restrict__ bo1,
   const float* __restrict__ bo2,
   float* __restrict__ C, float* __restrict__ msg2, float* __restrict__ retA) {
    __shared__ __bf16 Wb[8 * 8 * 64 * 8];   // [ks][mt][lane][jj], 64 KB
    int t = threadIdx.x;
    int wid = blockIdx.y;
    const float* W = (wid == 0) ? W1 : ((wid == 1) ? W2 : Wo1);
    for (int idx = t; idx < 32768; idx += 256) {
        int k = idx >> 7, m = idx & 127;   // coalesced read, m fastest
        Wb[(((k >> 5) * 8 + (m >> 4)) * 64 + ((k >> 3) & 3) * 16 + (m & 15)) * 8 + (k & 7)]
            = (__bf16)W[idx];
    }
    __syncthreads();

    int lane = t & 63, w = t >> 6;
    int n16 = lane & 15, quad = lane >> 4;
    int R = blockIdx.x * 64 + w * 16 + n16;   // feat row (tile never crosses batch)
    int b = R >> 8;
    const float* frow0 = nfeat  + (size_t)R * D_ + quad * 8;
    const float* frow1 = hidden + (size_t)R * D_ + quad * 8;

    bf16x8 bfrag[8];
#pragma unroll
    for (int ks = 0; ks < 8; ++ks) {
        const float* p = (ks < 4) ? (frow0 + ks * 32) : (frow1 + (ks - 4) * 32);
        floatx4 v0 = *(const floatx4*)p;
        floatx4 v1 = *(const floatx4*)(p + 4);
        bfrag[ks] = cvt8(v0, v1);
    }

    float* outp = (wid == 0) ? C : ((wid == 1) ? msg2 : retA);
#pragma unroll 2
    for (int mt = 0; mt < 8; ++mt) {
        floatx4 acc = (floatx4)0.f;
#pragma unroll
        for (int ks = 0; ks < 8; ++ks) {
            bf16x8 a = *(const bf16x8*)&Wb[((ks * 8 + mt) * 64 + lane) * 8];
            acc = mfma16(a, bfrag[ks], acc);
        }
        int m0 = mt * 16 + quad * 4;
        floatx4 add;
        if (wid == 0)      add = *(const floatx4*)&gplus[b * MID_ + m0];
        else if (wid == 1) add = *(const floatx4*)&b2[m0];
        else {
            floatx4 x = *(const floatx4*)&bo1[m0];
            floatx4 y = *(const floatx4*)&bo2[m0];
            add = x + y;
        }
        *(floatx4*)&outp[(size_t)R * MID_ + m0] = acc + add;
    }
}

// ---------------- kernel B: fused msg_e GEMM + broadcast-add + mask-max + out ----------------
// one block per (b, j); A = We^T (swizzled LDS), B = e-rows (global->reg).
// D layout: col = i (lane n16), row = m (quad*4+r)  ->  vectorized epilogue.
__global__ void __launch_bounds__(256, 4)
kB(const float* __restrict__ e, const float* __restrict__ We,
   const float* __restrict__ adj, const float* __restrict__ C,
   const float* __restrict__ msg2, const float* __restrict__ retA,
   const float* __restrict__ Wo2, float* __restrict__ out) {
    __shared__ __bf16 Wb[4 * 8 * 64 * 8];   // [ks][mt][lane][jj], 32 KB
    __shared__ float adj_sh[N_];
    __shared__ float C_sh[MID_];
    __shared__ float wmax[4][MID_];
    __shared__ float msgs_sh[MID_];
    __shared__ float part[2][MID_];

    int t = threadIdx.x;
    int b = blockIdx.x >> 8, j = blockIdx.x & 255;

    for (int idx = t; idx < 16384; idx += 256) {
        int k = idx >> 7, m = idx & 127;
        Wb[(((k >> 5) * 8 + (m >> 4)) * 64 + ((k >> 3) & 3) * 16 + (m & 15)) * 8 + (k & 7)]
            = (__bf16)We[idx];
    }
    adj_sh[t] = adj[b * N_ * N_ + t * N_ + j];
    if (t < 128) C_sh[t] = C[(b * N_ + j) * MID_ + t];
    __syncthreads();

    int lane = t & 63, w = t >> 6;
    int n16 = lane & 15, quad = lane >> 4;
    const float* ebase = e + (size_t)b * N_ * N_ * D_ + (size_t)j * D_ + quad * 8;
    const float* m2b   = msg2 + (size_t)b * N_ * MID_;

    floatx4 rm[8];
#pragma unroll
    for (int mt = 0; mt < 8; ++mt) rm[mt] = (floatx4)(-INFINITY);

    for (int pass = 0; pass < 2; ++pass) {
        int ibase = pass * 128 + w * 32;
        bf16x8 ef[2][4];
#pragma unroll
        for (int it = 0; it < 2; ++it) {
            const float* rowp = ebase + (size_t)(ibase + it * 16 + n16) * (N_ * D_);
#pragma unroll
            for (int ks = 0; ks < 4; ++ks) {
                floatx4 v0 = *(const floatx4*)(rowp + ks * 32);
                floatx4 v1 = *(const floatx4*)(rowp + ks * 32 + 4);
                ef[it][ks] = cvt8(v0, v1);
            }
        }
        float adj0 = adj_sh[ibase + n16];
        float adj1 = adj_sh[ibase + 16 + n16];
        const float* m2r0 = m2b + (size_t)(ibase + n16) * MID_;
        const float* m2r1 = m2b + (size_t)(ibase + 16 + n16) * MID_;

#pragma unroll 2
        for (int mt = 0; mt < 8; ++mt) {
            floatx4 a0 = (floatx4)0.f, a1 = (floatx4)0.f;
#pragma unroll
            for (int ks = 0; ks < 4; ++ks) {
                bf16x8 aW = *(const bf16x8*)&Wb[((ks * 8 + mt) * 64 + lane) * 8];
                a0 = mfma16(aW, ef[0][ks], a0);
                a1 = mfma16(aW, ef[1][ks], a1);
            }
            int m0 = mt * 16 + quad * 4;
            floatx4 c4  = *(const floatx4*)&C_sh[m0];
            floatx4 m20 = *(const floatx4*)&m2r0[m0];
            floatx4 m21 = *(const floatx4*)&m2r1[m0];
#pragma unroll
            for (int r = 0; r < 4; ++r) {
                float v0 = (a0[r] + c4[r] + m20[r]) * adj0;
                float v1 = (a1[r] + c4[r] + m21[r]) * adj1;
                rm[mt][r] = fmaxf(rm[mt][r], fmaxf(v0, v1));
            }
        }
    }

    // reduce over i (n16 lanes) via xor-shuffles, then stash per-wave result
#pragma unroll
    for (int mt = 0; mt < 8; ++mt) {
#pragma unroll
        for (int r = 0; r < 4; ++r) {
            float v = rm[mt][r];
            v = fmaxf(v, __shfl_xor(v, 1, 64));
            v = fmaxf(v, __shfl_xor(v, 2, 64));
            v = fmaxf(v, __shfl_xor(v, 4, 64));
            v = fmaxf(v, __shfl_xor(v, 8, 64));
            rm[mt][r] = v;
        }
    }
    if (n16 == 0) {
#pragma unroll
        for (int mt = 0; mt < 8; ++mt)
            *(floatx4*)&wmax[w][mt * 16 + quad * 4] = rm[mt];
    }
    __syncthreads();

    int m = t & 127, h = t >> 7;
    if (t < 128) {
        float mx = fmaxf(fmaxf(wmax[0][m], wmax[1][m]), fmaxf(wmax[2][m], wmax[3][m]));
        msgs_sh[m] = mx;
    }
    __syncthreads();

    // fused: ret = retA + msgs @ Wo2   (split-k over the two thread halves)
    float a2 = 0.f;
    for (int k = h * 64; k < h * 64 + 64; ++k)
        a2 += msgs_sh[k] * Wo2[k * MID_ + m];
    part[h][m] = a2;
    __syncthreads();
    if (t < 128) {
        int R = b * N_ + j;
        out[(size_t)R * MID_ + m] = retA[R * MID_ + m] + part[0][m] + part[1][m];
    }
}

extern "C" void kernel_launch(void* const* d_in, const int* in_sizes, int n_in,
                              void* d_out, int out_size, void* d_ws, size_t ws_size,
                              hipStream_t stream) {
    (void)in_sizes; (void)n_in; (void)out_size; (void)ws_size;
    const float* hidden = (const float*)d_in[0];
    const float* nfeat  = (const float*)d_in[1];
    const float* e      = (const float*)d_in[2];
    const float* g      = (const float*)d_in[3];
    const float* adj    = (const float*)d_in[4];
    const float* W1  = (const float*)d_in[5];
    const float* b1  = (const float*)d_in[6];
    const float* W2  = (const float*)d_in[7];
    const float* b2  = (const float*)d_in[8];
    const float* We  = (const float*)d_in[9];
    const float* be  = (const float*)d_in[10];
    const float* Wg  = (const float*)d_in[11];
    const float* bg  = (const float*)d_in[12];
    const float* Wo1 = (const float*)d_in[13];
    const float* bo1 = (const float*)d_in[14];
    const float* Wo2 = (const float*)d_in[15];
    const float* bo2 = (const float*)d_in[16];
    float* outp = (float*)d_out;

    float* ws    = (float*)d_ws;
    float* gplus = ws;                       // 1024
    float* C     = ws + 1024;                // 262144
    float* msg2  = C + 262144;               // 262144
    float* retA  = msg2 + 262144;            // 262144  (total ~3 MB)

    kG<<<1, 1024, 0, stream>>>(g, Wg, bg, b1, be, gplus);
    kA<<<dim3(32, 3), 256, 0, stream>>>(nfeat, hidden, W1, W2, Wo1, gplus,
                                        b2, bo1, bo2, C, msg2, retA);
    kB<<<2048, 256, 0, stream>>>(e, We, adj, C, msg2, retA, Wo2, outp);
}